// Round 11
// baseline (110.749 us; speedup 1.0000x reference)
//
#include <hip/hip_runtime.h>
#include <hip/hip_bf16.h>
#include <stdint.h>

typedef __attribute__((ext_vector_type(8))) short short8;
typedef __attribute__((ext_vector_type(8))) unsigned short ushort8;
typedef __attribute__((ext_vector_type(4))) float f32x4;
typedef __attribute__((ext_vector_type(4))) int int4v;

#define NHEAD 32
#define SEQ   2048
#define HN    128

static constexpr float INV_NORM = 0.08838834764831845f;  // 1/sqrt(128), folded into Q

__device__ __forceinline__ unsigned short f2bf(float f) {
  union { float f; unsigned u; } v; v.f = f;
  unsigned r = v.u + 0x7fffu + ((v.u >> 16) & 1u);   // RNE
  return (unsigned short)(r >> 16);
}

__device__ __forceinline__ f32x4 mfma16(short8 a, short8 b, f32x4 c) {
  return __builtin_amdgcn_mfma_f32_16x16x32_bf16(a, b, c, 0, 0, 0);
}

__device__ __forceinline__ void gl_lds16(const void* g, void* l) {
  __builtin_amdgcn_global_load_lds(
      (const __attribute__((address_space(1))) unsigned int*)g,
      (__attribute__((address_space(3))) unsigned int*)l, 16, 0, 0);
}

// ---- fused prep: K -> kswz (XOR-swizzled rows, proven, for LDS staging);
// V -> vfr (per-32kv-tile FRAGMENT layout, R8/R10-proven: V fragments are
// coalesced 1KB global loads in the main kernel, no LDS).
__global__ __launch_bounds__(256) void prep_kv(const float* __restrict__ K,
                                               const float* __restrict__ V,
                                               unsigned short* __restrict__ kswz,
                                               unsigned short* __restrict__ vfr) {
  __shared__ unsigned short lds[128 * 136];
  int bid = blockIdx.x;
  int tid = threadIdx.x;
  if (bid < 4096) {
    int idx = bid * 256 + tid;     // chunk id: 32*2048*16
    int cl = idx & 15;
    int t  = (idx >> 4) & 2047;
    int bn = idx >> 15;
    const float4* src = (const float4*)(K + ((size_t)t * 32 + bn) * 128 + cl * 8);
    float4 a = src[0], b = src[1];
    ushort8 o;
    o[0]=f2bf(a.x); o[1]=f2bf(a.y); o[2]=f2bf(a.z); o[3]=f2bf(a.w);
    o[4]=f2bf(b.x); o[5]=f2bf(b.y); o[6]=f2bf(b.z); o[7]=f2bf(b.w);
    *(ushort8*)(kswz + ((size_t)bn * 2048 + t) * 128 + ((cl ^ (t & 7)) * 8)) = o;
  } else {
    int vb = bid - 4096;
    int bn = vb >> 4;
    int t0 = (vb & 15) << 7;
    int r = tid >> 1, h0 = (tid & 1) * 64;
    const float* src = V + ((size_t)(t0 + r) * 32 + bn) * 128 + h0;
#pragma unroll
    for (int j = 0; j < 8; ++j) {
      float4 a = *(const float4*)(src + j * 8);
      float4 b = *(const float4*)(src + j * 8 + 4);
      ushort8 o;
      o[0]=f2bf(a.x); o[1]=f2bf(a.y); o[2]=f2bf(a.z); o[3]=f2bf(a.w);
      o[4]=f2bf(b.x); o[5]=f2bf(b.y); o[6]=f2bf(b.z); o[7]=f2bf(b.w);
      *(ushort8*)&lds[r * 136 + h0 + j * 8] = o;
    }
    __syncthreads();
    int h = tid >> 1, ts = (tid & 1) * 64;
    unsigned short tmp[64];
#pragma unroll
    for (int j = 0; j < 64; ++j) {
      int p = j & 31;
      int tloc = ((p >> 3) & 3) * 4 + ((p >> 2) & 1) * 16 + (p & 3);
      tmp[j] = lds[(ts + (j & 32) + tloc) * 136 + h];
    }
    // scatter 8-col groups into per-tile fragment layout (R8-proven)
#pragma unroll
    for (int j = 0; j < 8; ++j) {
      int c0 = t0 + ts + j * 8;          // column base (mult of 8)
      int tg = c0 >> 5;                  // 32-kv tile
      int hv = (c0 >> 3) & 3;            // hi group within tile
      size_t du = (size_t)bn * 32768 + (size_t)tg * 512 +
                  (h >> 4) * 64 + hv * 16 + (h & 15);
      *(ushort8*)(vfr + du * 8) = *(ushort8*)&tmp[j * 8];
    }
  }
}

// ---- fragment/softmax helpers --------------------------------------------
__device__ __forceinline__ void read_kf(const char* kb, int l15, int hi,
                                        short8 (&kf)[2][4]) {
  int xr = (l15 & 7) << 4;      // rows nt*16+l15: (row&7)==(l15&7), xr invariant
#pragma unroll
  for (int nt = 0; nt < 2; ++nt) {
    const char* krow = kb + (nt * 16 + l15) * 256;
#pragma unroll
    for (int kk = 0; kk < 4; ++kk)
      kf[nt][kk] = *(const short8*)(krow + (((kk * 4 + hi) * 16) ^ xr));
  }
}

__device__ __forceinline__ short8 packp(const float (&e)[8], float& da) {
  da += ((e[0] + e[1]) + (e[2] + e[3])) + ((e[4] + e[5]) + (e[6] + e[7]));
  unsigned w0, w1, w2, w3;
  asm("v_cvt_pk_bf16_f32 %0, %1, %2" : "=v"(w0) : "v"(e[0]), "v"(e[1]));
  asm("v_cvt_pk_bf16_f32 %0, %1, %2" : "=v"(w1) : "v"(e[2]), "v"(e[3]));
  asm("v_cvt_pk_bf16_f32 %0, %1, %2" : "=v"(w2) : "v"(e[4]), "v"(e[5]));
  asm("v_cvt_pk_bf16_f32 %0, %1, %2" : "=v"(w3) : "v"(e[6]), "v"(e[7]));
  union { int4v u; short8 s; } pk;
  pk.u = (int4v){(int)w0, (int)w1, (int)w2, (int)w3};
  return pk.s;
}

// Q pre-scaled by 1/sqrt(128): probability = exp(S) directly.
__device__ __forceinline__ short8 softp_m(const f32x4 (&sv)[2], int t0h, int qbase,
                                          int l15, int hi, float& da) {
  float e[8];
#pragma unroll
  for (int nt = 0; nt < 2; ++nt)
#pragma unroll
    for (int i = 0; i < 4; ++i) {
      float x = __expf(sv[nt][i]);
      int kv = t0h + nt * 16 + hi * 4 + i;
      e[nt * 4 + i] = (kv <= qbase + l15) ? x : 0.0f;
    }
  return packp(e, da);
}

__device__ __forceinline__ short8 softp_u(const f32x4 (&sv)[2], float& da) {
  float e[8];
#pragma unroll
  for (int nt = 0; nt < 2; ++nt)
#pragma unroll
    for (int i = 0; i < 4; ++i)
      e[nt * 4 + i] = __expf(sv[nt][i]);
  return packp(e, da);
}

// ---- main: R7 structure (512 blocks x 512 threads, 8 waves x 16 q-rows,
// pair-balanced qt, 2 blocks/CU = 4 waves/SIMD) with V OUT of LDS:
//   - K staged to LDS via gl_lds, KVB=32, double-buffered (16KB LDS).
//   - V read as 8 coalesced 1KB global loads from vfr, issued BEFORE the
//     K-stage prefetch each iteration so the stage loads are NEWER in the
//     vmcnt FIFO: the compiler's counted wait for vf before PV leaves the
//     stage in flight (R10's failure was the opposite order -> drain).
//   - top-of-loop vmcnt(0) sees ONLY the stage load (vf all consumed).
// LDS traffic per 32-kv iter: 8 waves x 8KB kf + 8KB stage = 72KB
// (R7: 144KB per half) -> port floor ~24us; K-only conflicts ~halve.
// V served by L1 (8 waves share the 8KB tile; gl_lds bypasses L1) and
// XCD-pinned L2 (bid%8 = bn%8).
__global__ __launch_bounds__(512, 2) void attn_main(const float* __restrict__ Q,
                                                    const unsigned short* __restrict__ kswz,
                                                    const unsigned short* __restrict__ vfr,
                                                    float* __restrict__ out) {
  // LDS: K only, double-buffered: 2 x 8KB = 16384
  __shared__ char smem[16384];
  int tid = threadIdx.x;
  int lane = tid & 63;
  int w = tid >> 6;                     // 0..7
  int l15 = lane & 15;
  int hi = lane >> 4;

  int bid = blockIdx.x;
  int bn = bid & 31;                    // head -> XCD bid%8 = bn%8 (stable)
  int z = bid >> 5;                     // [0,16)
  int qt = (z < 8) ? (15 - z) : (z - 8);  // pair {z,z+8} sums uniform
  int qb = qt * 128 + w * 16;           // this wave's 16 q-rows
  int ntile = 4 * qt + 4;               // 32-kv iterations

  // Q B-fragments, PRE-SCALED by 1/sqrt(128): softmax is exp(S) direct.
  short8 qf[4];
  {
    const float* qrow = Q + ((size_t)(qb + l15) * 32 + bn) * 128;
#pragma unroll
    for (int kk = 0; kk < 4; ++kk) {
      float4 a = *(const float4*)(qrow + kk * 32 + hi * 8);
      float4 b = *(const float4*)(qrow + kk * 32 + hi * 8 + 4);
      short8 o;
      o[0]=(short)f2bf(a.x*INV_NORM); o[1]=(short)f2bf(a.y*INV_NORM);
      o[2]=(short)f2bf(a.z*INV_NORM); o[3]=(short)f2bf(a.w*INV_NORM);
      o[4]=(short)f2bf(b.x*INV_NORM); o[5]=(short)f2bf(b.y*INV_NORM);
      o[6]=(short)f2bf(b.z*INV_NORM); o[7]=(short)f2bf(b.w*INV_NORM);
      qf[kk] = o;
    }
  }

  f32x4 zz = {0.f, 0.f, 0.f, 0.f};
  f32x4 acc[8];
#pragma unroll
  for (int ht = 0; ht < 8; ++ht) acc[ht] = zz;
  float dacc = 0.f;

  const char* kg = (const char*)(kswz + (size_t)bn * 2048 * 128);
  const char* vg = (const char*)vfr + (size_t)bn * 524288;   // 64 tiles x 8KB

  auto stage = [&](int buf, int t) {  // K 32-kv tile: ONE gl_lds per lane (8KB)
    gl_lds16(kg + (size_t)t * 8192 + tid * 16, smem + buf * 8192 + tid * 16);
  };

  // drain Q loads so in-loop vmcnt sees ONLY stage loads
  asm volatile("s_waitcnt vmcnt(0)" ::: "memory");
  stage(0, 0);

  int cur = 0;
  for (int it = 0; it < ntile; ++it) {
    int t0h = it * 32;
    asm volatile("s_waitcnt vmcnt(0)" ::: "memory");   // stage(it) landed
    __builtin_amdgcn_s_barrier();                      // all waves' stage done

    bool act = (t0h <= qb + 15);
    // V fragments FIRST (oldest in vmcnt FIFO): 8 coalesced 1KB loads
    short8 vf[8];
    if (act) {
      const char* vbg = vg + (size_t)it * 8192;
#pragma unroll
      for (int ht = 0; ht < 8; ++ht)
        vf[ht] = *(const short8*)(vbg + ht * 1024 + lane * 16);
    }
    // THEN prefetch next K tile (newer: waits for vf never drain it)
    if (it + 1 < ntile) stage(cur ^ 1, it + 1);

    if (act) {
      const char* kb = smem + cur * 8192;
      // K fragments from LDS
      short8 kf[2][4];
      read_kf(kb, l15, hi, kf);
      // QK^T (swapped): lane holds S^T[kv = 4hi+i (+16nt)][q = l15]
      f32x4 sv[2] = {zz, zz};
      __builtin_amdgcn_s_setprio(1);
#pragma unroll
      for (int nt = 0; nt < 2; ++nt)
#pragma unroll
        for (int kk = 0; kk < 4; ++kk)
          sv[nt] = mfma16(kf[nt][kk], qf[kk], sv[nt]);
      __builtin_amdgcn_s_setprio(0);
      bool mask = (t0h + 31 > qb);
      short8 p = mask ? softp_m(sv, t0h, qb, l15, hi, dacc)
                      : softp_u(sv, dacc);
      // PV (V rows pre-permuted to match P k-slot order); compiler emits a
      // counted vmcnt wait for vf here, stage load stays in flight
      __builtin_amdgcn_s_setprio(1);
#pragma unroll
      for (int ht = 0; ht < 8; ++ht)
        acc[ht] = mfma16(p, vf[ht], acc[ht]);
      __builtin_amdgcn_s_setprio(0);
    }
    cur ^= 1;
  }

  // denominator: reduce partials across hi (lanes l15 + 16*hi)
  {
    float d = dacc;
    d += __shfl_xor(d, 16);
    d += __shfl_xor(d, 32);
    dacc = d;                        // function of l15 only
  }
  float* dn = out + 8388608;
  if (hi == 0) dn[(size_t)bn * 2048 + qb + l15] = dacc;

  // per-output-row inverse denominators via lane broadcast
  float inv[4];
#pragma unroll
  for (int i = 0; i < 4; ++i)
    inv[i] = __builtin_amdgcn_rcpf(__shfl(dacc, hi * 4 + i));

  // ctx: out[s*4096 + bn*128 + h]; lane holds O[q = qb+4hi+i][h = 16ht+l15]
#pragma unroll
  for (int i = 0; i < 4; ++i) {
    float* orow = out + (size_t)(qb + hi * 4 + i) * 4096 + bn * 128 + l15;
#pragma unroll
    for (int ht = 0; ht < 8; ++ht)
      orow[ht * 16] = acc[ht][i] * inv[i];
  }
}

extern "C" void kernel_launch(void* const* d_in, const int* in_sizes, int n_in,
                              void* d_out, int out_size, void* d_ws, size_t ws_size,
                              hipStream_t stream) {
  const float* Q = (const float*)d_in[0];
  const float* K = (const float*)d_in[1];
  const float* V = (const float*)d_in[2];
  float* out = (float*)d_out;

  unsigned short* kswz = (unsigned short*)d_ws;
  unsigned short* vfr  = kswz + (size_t)NHEAD * SEQ * HN;

  prep_kv<<<4608, 256, 0, stream>>>(K, V, kswz, vfr);
  attn_main<<<512, 512, 0, stream>>>(Q, kswz, vfr, out);
}

// Round 12
// 80.216 us; speedup vs baseline: 1.3806x; 1.3806x over previous
//
#include <hip/hip_runtime.h>
#include <hip/hip_bf16.h>
#include <stdint.h>

typedef __attribute__((ext_vector_type(8))) short short8;
typedef __attribute__((ext_vector_type(8))) unsigned short ushort8;
typedef __attribute__((ext_vector_type(16))) float f32x16;
typedef __attribute__((ext_vector_type(4))) int int4v;

#define NHEAD 32
#define SEQ   2048
#define HN    128

static constexpr float INV_NORM = 0.08838834764831845f;  // 1/sqrt(128), folded into Q

__device__ __forceinline__ unsigned short f2bf(float f) {
  union { float f; unsigned u; } v; v.f = f;
  unsigned r = v.u + 0x7fffu + ((v.u >> 16) & 1u);   // RNE
  return (unsigned short)(r >> 16);
}

__device__ __forceinline__ f32x16 mfma32(short8 a, short8 b, f32x16 c) {
  return __builtin_amdgcn_mfma_f32_32x32x16_bf16(a, b, c, 0, 0, 0);
}

__device__ __forceinline__ void gl_lds16(const void* g, void* l) {
  __builtin_amdgcn_global_load_lds(
      (const __attribute__((address_space(1))) unsigned int*)g,
      (__attribute__((address_space(3))) unsigned int*)l, 16, 0, 0);
}

// ---- fused prep for the 32x32x16 MFMA path.
// kfr: per-32kv-tile fragment-linear K.  Chunk (tile, ks, lane) 16B holds
//   K[32*tile + (lane&31)][ks*16 + (lane>>5)*8 + m], m=0..7  (A-operand).
// vfr: per-32kv-tile fragment-linear V^T with the PV k-slot permutation:
//   chunk (tile, ht, ks, lane) 16B holds, for jj=0..7,
//   V[32*tile + 16ks + (jj&3) + 8*(jj>>2) + 4*(lane>>5)][ht*32 + (lane&31)]
// (same permutation applied to P's A-slots, so the contraction is exact).
__global__ __launch_bounds__(256) void prep_kv(const float* __restrict__ K,
                                               const float* __restrict__ V,
                                               unsigned short* __restrict__ kfr,
                                               unsigned short* __restrict__ vfr) {
  __shared__ unsigned short lds[128 * 136];
  int bid = blockIdx.x;
  int tid = threadIdx.x;
  if (bid < 4096) {
    int idx = bid * 256 + tid;     // chunk id: 32*2048*16
    int cl = idx & 15;             // 8-elem h chunk
    int t  = (idx >> 4) & 2047;    // kv row
    int bn = idx >> 15;            // head
    const float4* src = (const float4*)(K + ((size_t)t * 32 + bn) * 128 + cl * 8);
    float4 a = src[0], b = src[1];
    ushort8 o;
    o[0]=f2bf(a.x); o[1]=f2bf(a.y); o[2]=f2bf(a.z); o[3]=f2bf(a.w);
    o[4]=f2bf(b.x); o[5]=f2bf(b.y); o[6]=f2bf(b.z); o[7]=f2bf(b.w);
    // h = cl*8 -> ks = cl>>1, lane-half = cl&1; lane = (t&31) + 32*(cl&1)
    *(ushort8*)(kfr + (size_t)bn * 262144 + (size_t)(t >> 5) * 4096 +
                (cl >> 1) * 512 + (((t & 31) | ((cl & 1) << 5))) * 8) = o;
  } else {
    int vb = bid - 4096;
    int bn = vb >> 4;
    int t0 = (vb & 15) << 7;       // 128-kv window
    int r = tid >> 1, h0 = (tid & 1) * 64;
    const float* src = V + ((size_t)(t0 + r) * 32 + bn) * 128 + h0;
#pragma unroll
    for (int j = 0; j < 8; ++j) {
      float4 a = *(const float4*)(src + j * 8);
      float4 b = *(const float4*)(src + j * 8 + 4);
      ushort8 o;
      o[0]=f2bf(a.x); o[1]=f2bf(a.y); o[2]=f2bf(a.z); o[3]=f2bf(a.w);
      o[4]=f2bf(b.x); o[5]=f2bf(b.y); o[6]=f2bf(b.z); o[7]=f2bf(b.w);
      *(ushort8*)&lds[r * 136 + h0 + j * 8] = o;   // lds[kv_local][h]
    }
    __syncthreads();
    int h = tid >> 1, half64 = tid & 1;
    int ts = half64 * 64;          // this thread's 64-kv sub-window
    unsigned short val[64];
#pragma unroll
    for (int c = 0; c < 64; ++c) val[c] = lds[(ts + c) * 136 + h];
#pragma unroll
    for (int tg = 0; tg < 2; ++tg)       // 32-kv tile within sub-window
#pragma unroll
      for (int hb = 0; hb < 2; ++hb)     // lane half
#pragma unroll
        for (int ks = 0; ks < 2; ++ks) { // k-step
          ushort8 o;
#pragma unroll
          for (int jj = 0; jj < 8; ++jj)
            o[jj] = val[tg * 32 + ks * 16 + (jj & 3) + ((jj >> 2) << 3) + hb * 4];
          int T = (t0 >> 5) + half64 * 2 + tg;
          int lane = (h & 31) + hb * 32;
          *(ushort8*)(vfr + (size_t)bn * 262144 + (size_t)T * 4096 +
                      (((h >> 5) * 2 + ks)) * 512 + lane * 8) = o;
        }
  }
}

// ---- main: 32x32x16 MFMA.  512 blocks x 256 threads, 4 waves x 32 q-rows
// = 128-row q-tile.  Each wave reads the SAME 16KB K+V fragments per 32-kv
// tile as a 16-row wave would, but covers 2x the q-rows: per-output LDS
// traffic HALVES vs R7 (the measured binding resource, ~87% port util).
// 2 waves/SIMD by problem size (2048 32-row waves total) -- accepted;
// R0-family shows ~75% port util is sustained at 2 w/SIMD.
// KVB=64, double-buffered fragment-linear LDS (64KB, zero-conflict
// ds_read_b128, linear gl_lds staging), one barrier per 64 kv,
// pair-balanced qt ({z,z+8} sums 15), heavy blocks first.
// No tight reg cap needed at 2 w/SIMD: plain launch_bounds(256).
__global__ __launch_bounds__(256) void attn_main(const float* __restrict__ Q,
                                                 const unsigned short* __restrict__ kfr,
                                                 const unsigned short* __restrict__ vfr,
                                                 float* __restrict__ out) {
  // LDS: K 2x16KB | V 2x16KB = 65536 (fragment-linear)
  __shared__ char smem[65536];
  int tid = threadIdx.x;
  int lane = tid & 63;
  int w = tid >> 6;                     // 0..3
  int l31 = lane & 31;
  int hb = lane >> 5;

  int bid = blockIdx.x;
  int bn = bid & 31;                    // head -> XCD bid%8 = bn%8 (stable)
  int z = bid >> 5;                     // [0,16)
  int qt = (z < 8) ? (15 - z) : (z - 8);
  int qb = qt * 128 + w * 32;           // this wave's 32 q-rows
  int ntile = 2 * qt + 2;               // 64-kv iterations

  // Q B-fragments (32x32x16): lane holds Q[qb + l31][ks*16 + hb*8 + m],
  // PRE-SCALED by 1/sqrt(128).
  short8 qf[8];
  {
    const float* qrow = Q + ((size_t)(qb + l31) * 32 + bn) * 128;
#pragma unroll
    for (int ks = 0; ks < 8; ++ks) {
      const float* p = qrow + ks * 16 + hb * 8;
      float4 a = *(const float4*)p;
      float4 b = *(const float4*)(p + 4);
      short8 o;
      o[0]=(short)f2bf(a.x*INV_NORM); o[1]=(short)f2bf(a.y*INV_NORM);
      o[2]=(short)f2bf(a.z*INV_NORM); o[3]=(short)f2bf(a.w*INV_NORM);
      o[4]=(short)f2bf(b.x*INV_NORM); o[5]=(short)f2bf(b.y*INV_NORM);
      o[6]=(short)f2bf(b.z*INV_NORM); o[7]=(short)f2bf(b.w*INV_NORM);
      qf[ks] = o;
    }
  }

  f32x16 acc[4];
#pragma unroll
  for (int ht = 0; ht < 4; ++ht)
#pragma unroll
    for (int i = 0; i < 16; ++i) acc[ht][i] = 0.f;
  float dacc = 0.f;

  const char* kg = (const char*)kfr + (size_t)bn * 524288;
  const char* vg = (const char*)vfr + (size_t)bn * 524288;

  auto stage = [&](int buf, int it) {  // 64-kv pair of tiles: 8 gl_lds/thread
    const char* ks_ = kg + (size_t)it * 16384;
    const char* vs_ = vg + (size_t)it * 16384;
    char* kd = smem + buf * 16384;
    char* vd = smem + 32768 + buf * 16384;
#pragma unroll
    for (int r = 0; r < 4; ++r)
      gl_lds16(ks_ + (size_t)(tid + r * 256) * 16, kd + (tid + r * 256) * 16);
#pragma unroll
    for (int r = 0; r < 4; ++r)
      gl_lds16(vs_ + (size_t)(tid + r * 256) * 16, vd + (tid + r * 256) * 16);
  };

  // drain Q loads so in-loop vmcnt sees ONLY stage loads
  asm volatile("s_waitcnt vmcnt(0)" ::: "memory");
  stage(0, 0);

  int cur = 0;
  for (int it = 0; it < ntile; ++it) {
    asm volatile("s_waitcnt vmcnt(0)" ::: "memory");   // stage(it) landed
    __builtin_amdgcn_s_barrier();                      // all waves' stage done
    if (it + 1 < ntile) stage(cur ^ 1, it + 1);        // prefetch next pair

#pragma unroll
    for (int sub = 0; sub < 2; ++sub) {
      int t0h = it * 64 + sub * 32;
      if (t0h <= qb + 31) {
        const char* kb = smem + cur * 16384 + sub * 8192;
        const char* vb = smem + 32768 + cur * 16384 + sub * 8192;
        // QK^T (swapped): D[kv][q], A=K rows, B=Q.  Fragment-linear reads.
        f32x16 sv;
#pragma unroll
        for (int i = 0; i < 16; ++i) sv[i] = 0.f;
        __builtin_amdgcn_s_setprio(1);
#pragma unroll
        for (int ks = 0; ks < 8; ++ks) {
          short8 kf = *(const short8*)(kb + (ks * 64 + lane) * 16);
          sv = mfma32(kf, qf[ks], sv);
        }
        __builtin_amdgcn_s_setprio(0);
        // V fragments (latency hides under softmax)
        short8 vf[8];
#pragma unroll
        for (int c = 0; c < 8; ++c)
          vf[c] = *(const short8*)(vb + c * 1024 + lane * 16);
        // softmax (no max-subtraction).  S^T elem i: kv = (i&3)+8*(i>>2)+4hb.
        float e[16];
        if (t0h + 31 > qb) {
          int qr = qb + l31;
#pragma unroll
          for (int i = 0; i < 16; ++i) {
            float x = __expf(sv[i]);
            int kv = t0h + (i & 3) + ((i >> 2) << 3) + hb * 4;
            e[i] = (kv <= qr) ? x : 0.0f;
          }
        } else {
#pragma unroll
          for (int i = 0; i < 16; ++i) e[i] = __expf(sv[i]);
        }
        dacc += (((e[0]+e[1])+(e[2]+e[3])) + ((e[4]+e[5])+(e[6]+e[7]))) +
                (((e[8]+e[9])+(e[10]+e[11])) + ((e[12]+e[13])+(e[14]+e[15])));
        // pack P A-fragments: slot (ks, j) = e[ks*8 + j]
        short8 pA[2];
#pragma unroll
        for (int ks = 0; ks < 2; ++ks) {
          unsigned w0, w1, w2, w3;
          asm("v_cvt_pk_bf16_f32 %0, %1, %2" : "=v"(w0) : "v"(e[ks*8+0]), "v"(e[ks*8+1]));
          asm("v_cvt_pk_bf16_f32 %0, %1, %2" : "=v"(w1) : "v"(e[ks*8+2]), "v"(e[ks*8+3]));
          asm("v_cvt_pk_bf16_f32 %0, %1, %2" : "=v"(w2) : "v"(e[ks*8+4]), "v"(e[ks*8+5]));
          asm("v_cvt_pk_bf16_f32 %0, %1, %2" : "=v"(w3) : "v"(e[ks*8+6]), "v"(e[ks*8+7]));
          union { int4v u; short8 s; } pk;
          pk.u = (int4v){(int)w0, (int)w1, (int)w2, (int)w3};
          pA[ks] = pk.s;
        }
        // PV: D[q][h], A=P (k-slot permuted), B=V (rows pre-permuted SAME way)
        __builtin_amdgcn_s_setprio(1);
#pragma unroll
        for (int ht = 0; ht < 4; ++ht) {
          acc[ht] = mfma32(pA[0], vf[ht * 2 + 0], acc[ht]);
          acc[ht] = mfma32(pA[1], vf[ht * 2 + 1], acc[ht]);
        }
        __builtin_amdgcn_s_setprio(0);
      }
    }
    cur ^= 1;
  }

  // denominator: lanes l and l+32 hold complementary kv subsets for q=l31
  float d = dacc + __shfl_xor(dacc, 32);
  float* dn = out + 8388608;
  if (hb == 0) dn[(size_t)bn * 2048 + qb + l31] = d;

  // per-O-row inverse denominators: row(i) = (i&3)+8*(i>>2)+4hb
  float inv[16];
#pragma unroll
  for (int i = 0; i < 16; ++i)
    inv[i] = __builtin_amdgcn_rcpf(__shfl(d, (i & 3) + ((i >> 2) << 3) + hb * 4));

  // ctx: out[q*4096 + bn*128 + h]; C layout col=l31 (h within 32-tile),
  // row = (i&3)+8*(i>>2)+4hb (q within wave tile)
#pragma unroll
  for (int ht = 0; ht < 4; ++ht)
#pragma unroll
    for (int i = 0; i < 16; ++i) {
      int q = qb + (i & 3) + ((i >> 2) << 3) + hb * 4;
      out[(size_t)q * 4096 + bn * 128 + ht * 32 + l31] = acc[ht][i] * inv[i];
    }
}

extern "C" void kernel_launch(void* const* d_in, const int* in_sizes, int n_in,
                              void* d_out, int out_size, void* d_ws, size_t ws_size,
                              hipStream_t stream) {
  const float* Q = (const float*)d_in[0];
  const float* K = (const float*)d_in[1];
  const float* V = (const float*)d_in[2];
  float* out = (float*)d_out;

  unsigned short* kfr = (unsigned short*)d_ws;
  unsigned short* vfr = kfr + (size_t)NHEAD * SEQ * HN;

  prep_kv<<<4608, 256, 0, stream>>>(K, V, kfr, vfr);
  attn_main<<<512, 256, 0, stream>>>(Q, kfr, vfr, out);
}

// Round 13
// 73.818 us; speedup vs baseline: 1.5003x; 1.0867x over previous
//
#include <hip/hip_runtime.h>
#include <hip/hip_bf16.h>
#include <stdint.h>

typedef __attribute__((ext_vector_type(8))) short short8;
typedef __attribute__((ext_vector_type(8))) unsigned short ushort8;
typedef __attribute__((ext_vector_type(4))) float f32x4;
typedef __attribute__((ext_vector_type(4))) int int4v;

#define NHEAD 32
#define SEQ   2048
#define HN    128

static constexpr float INV_NORM = 0.08838834764831845f;  // 1/sqrt(128), folded into Q

__device__ __forceinline__ unsigned short f2bf(float f) {
  union { float f; unsigned u; } v; v.f = f;
  unsigned r = v.u + 0x7fffu + ((v.u >> 16) & 1u);   // RNE
  return (unsigned short)(r >> 16);
}

__device__ __forceinline__ f32x4 mfma16(short8 a, short8 b, f32x4 c) {
  return __builtin_amdgcn_mfma_f32_16x16x32_bf16(a, b, c, 0, 0, 0);
}

__device__ __forceinline__ void gl_lds16(const void* g, void* l) {
  __builtin_amdgcn_global_load_lds(
      (const __attribute__((address_space(1))) unsigned int*)g,
      (__attribute__((address_space(3))) unsigned int*)l, 16, 0, 0);
}

// ---- fused prep: K,V -> per-32kv-tile FRAGMENT-LINEAR layouts (R8-proven
// correct).  kfr chunk (tile, f=nt*4+kk, lane=hi*16+l15) 16B holds
//   K[32*tile + nt*16 + l15][kk*32 + hi*8 .. +8]        (QK^T A-operand)
// vfr chunk (tile, ht, lane=hi*16+l15) 16B holds
//   vT[ht*16 + l15][32*tile + hi*8 .. +8]  (PV B-operand, k-slot permuted)
// Main kernel stages these LINEARLY into LDS and reads them LINEARLY:
// address = base + (frag*64 + lane)*16 -> ZERO bank conflicts (R12-proven).
__global__ __launch_bounds__(256) void prep_kv(const float* __restrict__ K,
                                               const float* __restrict__ V,
                                               unsigned short* __restrict__ kfr,
                                               unsigned short* __restrict__ vfr) {
  __shared__ unsigned short lds[128 * 136];
  int bid = blockIdx.x;
  int tid = threadIdx.x;
  if (bid < 4096) {
    int idx = bid * 256 + tid;     // chunk id: 32*2048*16
    int cl = idx & 15;             // 8-elem column chunk
    int t  = (idx >> 4) & 2047;    // kv row
    int bn = idx >> 15;            // head
    const float4* src = (const float4*)(K + ((size_t)t * 32 + bn) * 128 + cl * 8);
    float4 a = src[0], b = src[1];
    ushort8 o;
    o[0]=f2bf(a.x); o[1]=f2bf(a.y); o[2]=f2bf(a.z); o[3]=f2bf(a.w);
    o[4]=f2bf(b.x); o[5]=f2bf(b.y); o[6]=f2bf(b.z); o[7]=f2bf(b.w);
    int tile = t >> 5, r = t & 31;
    int nt = r >> 4, lr = r & 15;
    int kk = cl >> 2, hc = cl & 3;
    *(ushort8*)(kfr + (size_t)bn * 262144 + tile * 4096 +
                (nt * 4 + kk) * 512 + (hc * 16 + lr) * 8) = o;
  } else {
    int vb = bid - 4096;
    int bn = vb >> 4;
    int t0 = (vb & 15) << 7;
    int r = tid >> 1, h0 = (tid & 1) * 64;
    const float* src = V + ((size_t)(t0 + r) * 32 + bn) * 128 + h0;
#pragma unroll
    for (int j = 0; j < 8; ++j) {
      float4 a = *(const float4*)(src + j * 8);
      float4 b = *(const float4*)(src + j * 8 + 4);
      ushort8 o;
      o[0]=f2bf(a.x); o[1]=f2bf(a.y); o[2]=f2bf(a.z); o[3]=f2bf(a.w);
      o[4]=f2bf(b.x); o[5]=f2bf(b.y); o[6]=f2bf(b.z); o[7]=f2bf(b.w);
      *(ushort8*)&lds[r * 136 + h0 + j * 8] = o;
    }
    __syncthreads();
    int h = tid >> 1, ts = (tid & 1) * 64;
    unsigned short tmp[64];
#pragma unroll
    for (int j = 0; j < 64; ++j) {
      int p = j & 31;
      int tloc = ((p >> 3) & 3) * 4 + ((p >> 2) & 1) * 16 + (p & 3);
      tmp[j] = lds[(ts + (j & 32) + tloc) * 136 + h];
    }
    // scatter 8-col groups into per-tile fragment layout (R8-proven)
#pragma unroll
    for (int j = 0; j < 8; ++j) {
      int c0 = t0 + ts + j * 8;          // column base (mult of 8)
      int tg = c0 >> 5;                  // 32-kv tile
      int hv = (c0 >> 3) & 3;            // hi group within tile
      size_t du = (size_t)bn * 32768 + (size_t)tg * 512 +
                  (h >> 4) * 64 + hv * 16 + (h & 15);
      *(ushort8*)(vfr + du * 8) = *(ushort8*)&tmp[j * 8];
    }
  }
}

__device__ __forceinline__ short8 packp(const float (&e)[8], float& da) {
  da += ((e[0] + e[1]) + (e[2] + e[3])) + ((e[4] + e[5]) + (e[6] + e[7]));
  unsigned w0, w1, w2, w3;
  asm("v_cvt_pk_bf16_f32 %0, %1, %2" : "=v"(w0) : "v"(e[0]), "v"(e[1]));
  asm("v_cvt_pk_bf16_f32 %0, %1, %2" : "=v"(w1) : "v"(e[2]), "v"(e[3]));
  asm("v_cvt_pk_bf16_f32 %0, %1, %2" : "=v"(w2) : "v"(e[4]), "v"(e[5]));
  asm("v_cvt_pk_bf16_f32 %0, %1, %2" : "=v"(w3) : "v"(e[6]), "v"(e[7]));
  union { int4v u; short8 s; } pk;
  pk.u = (int4v){(int)w0, (int)w1, (int)w2, (int)w3};
  return pk.s;
}

// Q pre-scaled by 1/sqrt(128): probability = exp(S) directly.
__device__ __forceinline__ short8 softp_m(const f32x4 (&sv)[2], int t0h, int qbase,
                                          int l15, int hi, float& da) {
  float e[8];
#pragma unroll
  for (int nt = 0; nt < 2; ++nt)
#pragma unroll
    for (int i = 0; i < 4; ++i) {
      float x = __expf(sv[nt][i]);
      int kv = t0h + nt * 16 + hi * 4 + i;
      e[nt * 4 + i] = (kv <= qbase + l15) ? x : 0.0f;
    }
  return packp(e, da);
}

__device__ __forceinline__ short8 softp_u(const f32x4 (&sv)[2], float& da) {
  float e[8];
#pragma unroll
  for (int nt = 0; nt < 2; ++nt)
#pragma unroll
    for (int i = 0; i < 4; ++i)
      e[nt * 4 + i] = __expf(sv[nt][i]);
  return packp(e, da);
}

// ---- main: R7 champion structure VERBATIM (512 blocks x 512 threads,
// 8 waves x 16 q-rows = 128-row q-tile, KVB=64 double-buffered 64KB LDS,
// one barrier per 64 kv, pair-balanced qt {z,z+8}, 2 blocks/CU = 4
// waves/SIMD) with ONE change: fragment-linear LDS layouts.  R7 was ~96%
// LDS-port-limited incl. 16.6K cyc/CU of bank conflicts from the V-read
// permutation; fragment-linear reads (addr = base + (frag*64+lane)*16)
// measured ZERO conflicts in R12.  Operand-to-lane mapping is identical
// to R7's, so all math (softmax, PV, epilogue) is unchanged.
// __launch_bounds__(512,2): reg cap 128 (cap=256/w, R1/R3-established).
__global__ __launch_bounds__(512, 2) void attn_main(const float* __restrict__ Q,
                                                    const unsigned short* __restrict__ kfr,
                                                    const unsigned short* __restrict__ vfr,
                                                    float* __restrict__ out) {
  // LDS: K 2x16KB | V 2x16KB (each 16KB = two 8KB 32-kv tiles) = 65536
  __shared__ char smem[65536];
  int tid = threadIdx.x;
  int lane = tid & 63;
  int w = tid >> 6;                     // 0..7
  int l15 = lane & 15;
  int hi = lane >> 4;

  int bid = blockIdx.x;
  int bn = bid & 31;                    // head -> XCD bid%8 = bn%8 (stable)
  int z = bid >> 5;                     // [0,16)
  int qt = (z < 8) ? (15 - z) : (z - 8);
  int qb = qt * 128 + w * 16;           // this wave's 16 q-rows
  int ntile = 2 * qt + 2;               // 64-kv iterations

  // Q B-fragments, PRE-SCALED by 1/sqrt(128): softmax is exp(S) direct.
  short8 qf[4];
  {
    const float* qrow = Q + ((size_t)(qb + l15) * 32 + bn) * 128;
#pragma unroll
    for (int kk = 0; kk < 4; ++kk) {
      float4 a = *(const float4*)(qrow + kk * 32 + hi * 8);
      float4 b = *(const float4*)(qrow + kk * 32 + hi * 8 + 4);
      short8 o;
      o[0]=(short)f2bf(a.x*INV_NORM); o[1]=(short)f2bf(a.y*INV_NORM);
      o[2]=(short)f2bf(a.z*INV_NORM); o[3]=(short)f2bf(a.w*INV_NORM);
      o[4]=(short)f2bf(b.x*INV_NORM); o[5]=(short)f2bf(b.y*INV_NORM);
      o[6]=(short)f2bf(b.z*INV_NORM); o[7]=(short)f2bf(b.w*INV_NORM);
      qf[kk] = o;
    }
  }

  f32x4 zz = {0.f, 0.f, 0.f, 0.f};
  f32x4 acc[8];
#pragma unroll
  for (int ht = 0; ht < 8; ++ht) acc[ht] = zz;
  float dacc = 0.f;

  const char* kg = (const char*)kfr + (size_t)bn * 524288;   // 64 tiles x 8KB
  const char* vg = (const char*)vfr + (size_t)bn * 524288;   // 64 tiles x 8KB

  auto stage = [&](int buf, int it) {  // 64-kv: 16KB K + 16KB V, linear copy
    const char* ks_ = kg + (size_t)it * 16384;
    char* kd = smem + buf * 16384;
    gl_lds16(ks_ + (size_t)tid * 16, kd + tid * 16);
    gl_lds16(ks_ + (size_t)(tid + 512) * 16, kd + (tid + 512) * 16);
    const char* vs_ = vg + (size_t)it * 16384;
    char* vd = smem + 32768 + buf * 16384;
    gl_lds16(vs_ + (size_t)tid * 16, vd + tid * 16);
    gl_lds16(vs_ + (size_t)(tid + 512) * 16, vd + (tid + 512) * 16);
  };

  // drain Q loads so in-loop vmcnt sees ONLY stage loads
  asm volatile("s_waitcnt vmcnt(0)" ::: "memory");
  stage(0, 0);

  int cur = 0;
  for (int it = 0; it < ntile; ++it) {
    int t0 = it * 64;
    asm volatile("s_waitcnt vmcnt(0)" ::: "memory");   // stage(it) landed
    __builtin_amdgcn_s_barrier();                      // all waves' stage done
    if (it + 1 < ntile) stage(cur ^ 1, it + 1);        // prefetch next tile

    const char* kb = smem + cur * 16384;
    const char* vb = smem + 32768 + cur * 16384;
#pragma unroll
    for (int half = 0; half < 2; ++half) {
      int t0h = t0 + half * 32;
      if (t0h <= qb + 15) {
        const char* kbh = kb + half * 8192;
        const char* vbh = vb + half * 8192;
        // K fragments: linear ds_read_b128, zero conflicts
        short8 kf[2][4];
#pragma unroll
        for (int nt = 0; nt < 2; ++nt)
#pragma unroll
          for (int kk = 0; kk < 4; ++kk)
            kf[nt][kk] = *(const short8*)(kbh + ((nt * 4 + kk) * 64 + lane) * 16);
        // QK^T (swapped): lane holds S^T[kv = 4hi+i (+16nt)][q = l15]
        f32x4 sv[2] = {zz, zz};
        __builtin_amdgcn_s_setprio(1);
#pragma unroll
        for (int nt = 0; nt < 2; ++nt)
#pragma unroll
          for (int kk = 0; kk < 4; ++kk)
            sv[nt] = mfma16(kf[nt][kk], qf[kk], sv[nt]);
        __builtin_amdgcn_s_setprio(0);
        // V fragments: linear ds_read_b128; latency hides under softmax
        short8 vf[8];
#pragma unroll
        for (int ht = 0; ht < 8; ++ht)
          vf[ht] = *(const short8*)(vbh + (ht * 64 + lane) * 16);
        bool mask = (t0h + 31 > qb);
        short8 p = mask ? softp_m(sv, t0h, qb, l15, hi, dacc)
                        : softp_u(sv, dacc);
        // PV (V rows pre-permuted to match P k-slot order)
        __builtin_amdgcn_s_setprio(1);
#pragma unroll
        for (int ht = 0; ht < 8; ++ht)
          acc[ht] = mfma16(p, vf[ht], acc[ht]);
        __builtin_amdgcn_s_setprio(0);
      }
    }
    cur ^= 1;
  }

  // denominator: reduce partials across hi (lanes l15 + 16*hi)
  {
    float d = dacc;
    d += __shfl_xor(d, 16);
    d += __shfl_xor(d, 32);
    dacc = d;                        // function of l15 only
  }
  float* dn = out + 8388608;
  if (hi == 0) dn[(size_t)bn * 2048 + qb + l15] = dacc;

  // per-output-row inverse denominators via lane broadcast
  float inv[4];
#pragma unroll
  for (int i = 0; i < 4; ++i)
    inv[i] = __builtin_amdgcn_rcpf(__shfl(dacc, hi * 4 + i));

  // ctx: out[s*4096 + bn*128 + h]; lane holds O[q = qb+4hi+i][h = 16ht+l15]
#pragma unroll
  for (int i = 0; i < 4; ++i) {
    float* orow = out + (size_t)(qb + hi * 4 + i) * 4096 + bn * 128 + l15;
#pragma unroll
    for (int ht = 0; ht < 8; ++ht)
      orow[ht * 16] = acc[ht][i] * inv[i];
  }
}

extern "C" void kernel_launch(void* const* d_in, const int* in_sizes, int n_in,
                              void* d_out, int out_size, void* d_ws, size_t ws_size,
                              hipStream_t stream) {
  const float* Q = (const float*)d_in[0];
  const float* K = (const float*)d_in[1];
  const float* V = (const float*)d_in[2];
  float* out = (float*)d_out;

  unsigned short* kfr = (unsigned short*)d_ws;
  unsigned short* vfr = kfr + (size_t)NHEAD * SEQ * HN;

  prep_kv<<<4608, 256, 0, stream>>>(K, V, kfr, vfr);
  attn_main<<<512, 512, 0, stream>>>(Q, kfr, vfr, out);
}